// Round 8
// baseline (301.411 us; speedup 1.0000x reference)
//
#include <hip/hip_runtime.h>
#include <hip/hip_fp16.h>

namespace {

constexpr int T_STEPS = 256;
constexpr int HD = 50;    // hidden size
constexpr int HP = 64;    // padded hidden
constexpr int KST = 88;   // h-buf row stride in fp16 elems
constexpr int KSTS = 72;  // weight staging stride
constexpr int BT = 16;    // batch tile per block
constexpr int NTHR = 192; // 3 waves = 3 layers; self-recurrence intra-wave
constexpr int XST = 34;   // xls row stride in floats
constexpr int LAY_SH = BT * KST;     // shorts per (slot, layer)
constexpr int SLOT_SH = 3 * LAY_SH;  // shorts per ring slot

typedef __attribute__((ext_vector_type(8))) _Float16 f16x8;
typedef __attribute__((ext_vector_type(4))) float f32x4;

__device__ __forceinline__ unsigned short f2h(float x) {
  __half h = __float2half(x);
  return *reinterpret_cast<unsigned short*>(&h);
}
__device__ __forceinline__ float h2f(unsigned short u) {
  __half h;
  *reinterpret_cast<unsigned short*>(&h) = u;
  return __half2float(h);
}
__device__ __forceinline__ float fast_tanh(float x) {
  float e = __expf(2.0f * x);
  return 1.0f - 2.0f * __builtin_amdgcn_rcpf(e + 1.0f);
}

#define MFMA16 __builtin_amdgcn_mfma_f32_16x16x32_f16

// 3 waves = 3 layers. Each wave computes its ENTIRE layer (M=50 as 4 tiles of 16,
// N=16 batch, K=64 padded): self-recurrence is INTRA-WAVE (own LDS write -> own
// read, same-wave DS ordering, no barrier dependency), cross-layer goes through
// the 3-slot ring with 2-iter slack (prefetched 1 iter ahead, barrier-synced).
// This cuts LDS reads 4x vs the 12-wave M-split (no B-frag replication) and
// removes the sibling-wave barrier coupling that caused the R6 serialization tail.
__global__ __launch_bounds__(NTHR, 1) void rnn3_kernel(
    const float* __restrict__ x,
    const float* __restrict__ Wih1, const float* __restrict__ Whh1,
    const float* __restrict__ bih1, const float* __restrict__ bhh1,
    const float* __restrict__ Wih2, const float* __restrict__ Whh2,
    const float* __restrict__ bih2, const float* __restrict__ bhh2,
    const float* __restrict__ Wih3, const float* __restrict__ Whh3,
    const float* __restrict__ bih3, const float* __restrict__ bhh3,
    const float* __restrict__ fcw, const float* __restrict__ fcb,
    float* __restrict__ out) {
  __shared__ unsigned short hbuf[3 * SLOT_SH];  // [ring][layer][b*KST+k], fp16 bits
  __shared__ float xls[T_STEPS][XST];           // staged x
  __shared__ unsigned short scr[2][HP * KSTS];  // weight staging (hi / scaled-lo)

  const int tid = threadIdx.x;
  const int myL = tid >> 6;      // wave = layer 0..2
  const int lane = tid & 63;
  const int quad = lane >> 4;
  const int l15 = lane & 15;
  const int b0 = blockIdx.x * BT;

  // zero all 3 ring slots
  {
    unsigned int* hz = reinterpret_cast<unsigned int*>(hbuf);
    const int n = 3 * SLOT_SH / 2;
    for (int i = tid; i < n; i += NTHR) hz[i] = 0u;
  }
  // stage x -> LDS
  for (int idx = tid; idx < BT * T_STEPS; idx += NTHR) {
    int b = idx >> 8, t = idx & 255;
    float2 v = *reinterpret_cast<const float2*>(x + (size_t)(b0 + b) * (T_STEPS * 2) + 2 * t);
    xls[t][2 * b] = v.x;
    xls[t][2 * b + 1] = v.y;
  }

  // ---- stage the five 50x50 matrices: fp16 hi + scaled fp16 lo ----
  const float* mats[5] = {Whh1, Wih2, Whh2, Wih3, Whh3};
  constexpr int matL[5] = {0, 1, 1, 2, 2};
  constexpr int matS[5] = {1, 0, 1, 0, 1};  // slot0 = cross (unused for L0), slot1 = self
  f16x8 wAh[2][4][2], wAl[2][4][2];  // [slot][tile][kstep]
#pragma unroll
  for (int sl = 0; sl < 2; ++sl)
#pragma unroll
    for (int t = 0; t < 4; ++t)
#pragma unroll
      for (int ks = 0; ks < 2; ++ks) { wAh[sl][t][ks] = f16x8(0); wAl[sl][t][ks] = f16x8(0); }

#pragma unroll
  for (int m = 0; m < 5; ++m) {
    __syncthreads();
    const float* W = mats[m];
    for (int idx = tid; idx < HP * HP; idx += NTHR) {
      int i = idx >> 6, k = idx & 63;
      float v = (i < HD && k < HD) ? W[i * HD + k] : 0.0f;
      unsigned short hi = f2h(v);
      scr[0][i * KSTS + k] = hi;
      scr[1][i * KSTS + k] = f2h((v - h2f(hi)) * 2048.0f);  // scaled residual
    }
    __syncthreads();
    if (myL == matL[m]) {
      const int sl = matS[m];
#pragma unroll
      for (int t = 0; t < 4; ++t) {
        const int arow = 16 * t + l15;
#pragma unroll
        for (int ks = 0; ks < 2; ++ks) {
          wAh[sl][t][ks] = *reinterpret_cast<const f16x8*>(&scr[0][arow * KSTS + 32 * ks + 8 * quad]);
          wAl[sl][t][ks] = *reinterpret_cast<const f16x8*>(&scr[1][arow * KSTS + 32 * ks + 8 * quad]);
        }
      }
    }
  }

  // per-lane C-row constants per tile (i = 16t + 4*quad + r)
  const float* bi = (myL == 0) ? bih1 : (myL == 1) ? bih2 : bih3;
  const float* bh = (myL == 0) ? bhh1 : (myL == 1) ? bhh2 : bhh3;
  float bsc[4][4], wx0[4][4], wx1[4][4];
  f32x4 bsv[4];  // static C-init for L1/L2
#pragma unroll
  for (int t = 0; t < 4; ++t)
#pragma unroll
    for (int r = 0; r < 4; ++r) {
      int i = 16 * t + 4 * quad + r;
      bool v = i < HD;
      bsc[t][r] = v ? (bi[i] + bh[i]) : 0.0f;
      wx0[t][r] = (v && myL == 0) ? Wih1[i * 2 + 0] : 0.0f;
      wx1[t][r] = (v && myL == 0) ? Wih1[i * 2 + 1] : 0.0f;
      bsv[t][r] = bsc[t][r];
    }

  const int ldsOffR = l15 * KST + 8 * quad;
  const unsigned short* sbase = hbuf + myL * LAY_SH + ldsOffR;                       // self reads
  const unsigned short* cbase = hbuf + ((myL > 0) ? myL - 1 : 0) * LAY_SH + ldsOffR; // cross reads
  unsigned short* wbase = hbuf + myL * LAY_SH + l15 * KST + 4 * quad;                // writes (+16t)
  constexpr float INV = 4.8828125e-4f;  // 2^-11

  f16x8 bS0 = f16x8(0), bS1 = f16x8(0);  // self B-frags for CURRENT iter (h_{-1}=0)
  f16x8 pf0 = f16x8(0), pf1 = f16x8(0);  // cross B-frags for CURRENT iter
  f32x4 zero4 = {0.f, 0.f, 0.f, 0.f};

  __syncthreads();
  float2 xcur = (myL == 0) ? *reinterpret_cast<const float2*>(&xls[0][2 * l15])
                           : make_float2(0.f, 0.f);

  // one step: iter s computes h1_s, h2_{s-2}, h3_{s-4}; wr = s%3, rd2 = (s+2)%3
  auto step = [&](int s, int wr, int rd2, bool act) {
    if (act) {
      f32x4 c1[4], c2[4];
      if (myL == 0) {
#pragma unroll
        for (int t = 0; t < 4; ++t) {
          f32x4 ci;
#pragma unroll
          for (int r = 0; r < 4; ++r) ci[r] = bsc[t][r] + wx0[t][r] * xcur.x + wx1[t][r] * xcur.y;
          c1[t] = MFMA16(wAh[1][t][0], bS0, ci, 0, 0, 0);
          c2[t] = MFMA16(wAl[1][t][0], bS0, zero4, 0, 0, 0);
          c1[t] = MFMA16(wAh[1][t][1], bS1, c1[t], 0, 0, 0);
          c2[t] = MFMA16(wAl[1][t][1], bS1, c2[t], 0, 0, 0);
        }
        int sn = (s + 1 < T_STEPS) ? s + 1 : T_STEPS - 1;
        xcur = *reinterpret_cast<const float2*>(&xls[sn][2 * l15]);
      } else {
#pragma unroll
        for (int t = 0; t < 4; ++t) {
          c1[t] = MFMA16(wAh[0][t][0], pf0, bsv[t], 0, 0, 0);
          c2[t] = MFMA16(wAl[0][t][0], pf0, zero4, 0, 0, 0);
          c1[t] = MFMA16(wAh[0][t][1], pf1, c1[t], 0, 0, 0);
          c2[t] = MFMA16(wAl[0][t][1], pf1, c2[t], 0, 0, 0);
          c1[t] = MFMA16(wAh[1][t][0], bS0, c1[t], 0, 0, 0);
          c2[t] = MFMA16(wAl[1][t][0], bS0, c2[t], 0, 0, 0);
          c1[t] = MFMA16(wAh[1][t][1], bS1, c1[t], 0, 0, 0);
          c2[t] = MFMA16(wAl[1][t][1], bS1, c2[t], 0, 0, 0);
        }
      }
      // tanh -> fp16 -> 4 packed 8B writes (this wave owns ALL rows of its layer)
#pragma unroll
      for (int t = 0; t < 4; ++t) {
        unsigned short ht[4];
#pragma unroll
        for (int r = 0; r < 4; ++r) ht[r] = f2h(fast_tanh(c1[t][r] + c2[t][r] * INV));
        unsigned int h01 = (unsigned int)ht[0] | ((unsigned int)ht[1] << 16);
        unsigned int h23 = (unsigned int)ht[2] | ((unsigned int)ht[3] << 16);
        *reinterpret_cast<uint2*>(wbase + wr * SLOT_SH + 16 * t) = make_uint2(h01, h23);
      }
    }
    // self B-frags for next iter: OWN writes this iter (slot wr) — same-wave DS
    // ordering makes this safe pre-barrier; latency hidden across the barrier.
    bS0 = *reinterpret_cast<const f16x8*>(sbase + wr * SLOT_SH);
    bS1 = *reinterpret_cast<const f16x8*>(sbase + wr * SLOT_SH + 32);
    // cross B-frags for next iter: data written at s-1 (slot rd2), barrier-synced.
    if (myL > 0) {
      pf0 = *reinterpret_cast<const f16x8*>(cbase + rd2 * SLOT_SH);
      pf1 = *reinterpret_cast<const f16x8*>(cbase + rd2 * SLOT_SH + 32);
    }
    __syncthreads();
  };

  auto actOf = [&](int s) {
    return (myL == 0) ? (s < T_STEPS)
         : (myL == 1) ? (s >= 2 && s < T_STEPS + 2)
                      : (s >= 4);
  };

  // prologue s=0..3
  for (int s = 0; s < 4; ++s) step(s, s % 3, (s + 2) % 3, actOf(s));
  // steady s=4..255: all waves active, literal ring slots
  for (int sb = 4; sb < 256; sb += 3) {
    step(sb + 0, 1, 0, true);
    step(sb + 1, 2, 1, true);
    step(sb + 2, 0, 2, true);
  }
  // epilogue s=256..259
  for (int s = 256; s < 260; ++s) step(s, s % 3, (s + 2) % 3, actOf(s));

  // ---- fc epilogue: h3_255 written at s=259 -> slot 259%3 = 1 ----
  if (tid < BT * 2) {
    int b = tid >> 1, o = tid & 1;
    const unsigned short* h3 = hbuf + 1 * SLOT_SH + 2 * LAY_SH + b * KST;
    float acc = fcb[o];
    for (int i = 0; i < HD; ++i) acc += fcw[o * HD + i] * h2f(h3[i]);
    out[(size_t)(b0 + b) * 2 + o] = acc;
  }
}

}  // namespace

extern "C" void kernel_launch(void* const* d_in, const int* in_sizes, int n_in,
                              void* d_out, int out_size, void* d_ws, size_t ws_size,
                              hipStream_t stream) {
  const float* x = (const float*)d_in[0];
  const float* Wih1 = (const float*)d_in[1];
  const float* Whh1 = (const float*)d_in[2];
  const float* bih1 = (const float*)d_in[3];
  const float* bhh1 = (const float*)d_in[4];
  const float* Wih2 = (const float*)d_in[5];
  const float* Whh2 = (const float*)d_in[6];
  const float* bih2 = (const float*)d_in[7];
  const float* bhh2 = (const float*)d_in[8];
  const float* Wih3 = (const float*)d_in[9];
  const float* Whh3 = (const float*)d_in[10];
  const float* bih3 = (const float*)d_in[11];
  const float* bhh3 = (const float*)d_in[12];
  const float* fcw = (const float*)d_in[13];
  const float* fcb = (const float*)d_in[14];

  rnn3_kernel<<<4096 / BT, NTHR, 0, stream>>>(x, Wih1, Whh1, bih1, bhh1,
                                              Wih2, Whh2, bih2, bhh2,
                                              Wih3, Whh3, bih3, bhh3,
                                              fcw, fcb, (float*)d_out);
}

// Round 9
// 196.932 us; speedup vs baseline: 1.5305x; 1.5305x over previous
//
#include <hip/hip_runtime.h>
#include <hip/hip_fp16.h>

namespace {

constexpr int T_STEPS = 256;
constexpr int HD = 50;    // hidden size
constexpr int HP = 64;    // padded hidden
constexpr int KST = 88;   // h-buf row stride in fp16 elems
constexpr int KSTS = 72;  // weight staging stride
constexpr int BT = 16;    // batch tile per block
constexpr int NTHR = 768; // 12 waves: (layer, M-tile) — measured-best config
constexpr int XST = 34;   // xls row stride in floats
constexpr int LAY_SH = BT * KST;     // shorts per (slot, layer)
constexpr int SLOT_SH = 3 * LAY_SH;  // shorts per ring slot

typedef __attribute__((ext_vector_type(8))) _Float16 f16x8;
typedef __attribute__((ext_vector_type(4))) float f32x4;

__device__ __forceinline__ unsigned short f2h(float x) {
  __half h = __float2half(x);  // RNE
  return *reinterpret_cast<unsigned short*>(&h);
}
__device__ __forceinline__ float h2f(unsigned short u) {
  __half h;
  *reinterpret_cast<unsigned short*>(&h) = u;
  return __half2float(h);
}

#define MFMA16 __builtin_amdgcn_mfma_f32_16x16x32_f16

// R6 skeleton (12 waves = layer x M-tile, fp16 h, diagonal 0/2/4, 3-slot ring,
// literal-slot steady-state unroll) with the arithmetic thinned:
//  - W single fp16 (lo-term dropped): MFMA 8->4 per wave, absmax ~2x (budgeted)
//  - batched-rcp tanh: ONE v_rcp for 4 values (trans ops 8->5 per wave/iter)
//  - C-init folded into first MFMA's C operand (loop-invariant bsv register)
__global__ __launch_bounds__(NTHR, 3) void rnn3_kernel(
    const float* __restrict__ x,
    const float* __restrict__ Wih1, const float* __restrict__ Whh1,
    const float* __restrict__ bih1, const float* __restrict__ bhh1,
    const float* __restrict__ Wih2, const float* __restrict__ Whh2,
    const float* __restrict__ bih2, const float* __restrict__ bhh2,
    const float* __restrict__ Wih3, const float* __restrict__ Whh3,
    const float* __restrict__ bih3, const float* __restrict__ bhh3,
    const float* __restrict__ fcw, const float* __restrict__ fcb,
    float* __restrict__ out) {
  __shared__ unsigned short hbuf[3 * SLOT_SH];  // [ring][layer][b*KST+k], fp16 bits
  __shared__ float xls[T_STEPS][XST];           // staged x
  __shared__ unsigned short scr[HP * KSTS];     // weight staging (fp16)

  const int tid = threadIdx.x;
  const int w = tid >> 6;
  const int myL = w >> 2;        // layer 0..2
  const int wv = w & 3;          // M-tile
  const int lane = tid & 63;
  const int quad = lane >> 4;
  const int l15 = lane & 15;
  const int b0 = blockIdx.x * BT;

  // zero all 3 ring slots (initial h=0 and the k>=HD pad)
  {
    unsigned int* hz = reinterpret_cast<unsigned int*>(hbuf);
    const int n = 3 * SLOT_SH / 2;
    for (int i = tid; i < n; i += NTHR) hz[i] = 0u;
  }
  // stage x -> LDS
  for (int idx = tid; idx < BT * T_STEPS; idx += NTHR) {
    int b = idx >> 8, t = idx & 255;
    float2 v = *reinterpret_cast<const float2*>(x + (size_t)(b0 + b) * (T_STEPS * 2) + 2 * t);
    xls[t][2 * b] = v.x;
    xls[t][2 * b + 1] = v.y;
  }

  // ---- stage the five 50x50 matrices as fp16 ----
  const float* mats[5] = {Whh1, Wih2, Whh2, Wih3, Whh3};
  constexpr int matL[5] = {0, 1, 1, 2, 2};
  constexpr int matS[5] = {0, 0, 1, 0, 1};  // slot0 = cross (self for L0), slot1 = self
  f16x8 wA[2][2];  // [slot][kstep]
#pragma unroll
  for (int sl = 0; sl < 2; ++sl)
#pragma unroll
    for (int ks = 0; ks < 2; ++ks) wA[sl][ks] = f16x8(0);

  const int arow = 16 * wv + l15;
#pragma unroll
  for (int m = 0; m < 5; ++m) {
    __syncthreads();
    const float* W = mats[m];
    for (int idx = tid; idx < HP * HP; idx += NTHR) {
      int i = idx >> 6, k = idx & 63;
      float v = (i < HD && k < HD) ? W[i * HD + k] : 0.0f;
      scr[i * KSTS + k] = f2h(v);
    }
    __syncthreads();
    if (myL == matL[m]) {
      const int sl = matS[m];
      const unsigned short* ph = &scr[arow * KSTS + 8 * quad];
      wA[sl][0] = *reinterpret_cast<const f16x8*>(ph);
      wA[sl][1] = *reinterpret_cast<const f16x8*>(ph + 32);
    }
  }

  // per-lane C-row constants
  const int ic = 16 * wv + 4 * quad;
  const float* bi = (myL == 0) ? bih1 : (myL == 1) ? bih2 : bih3;
  const float* bh = (myL == 0) ? bhh1 : (myL == 1) ? bhh2 : bhh3;
  float wx0[4], wx1[4];
  f32x4 bsv;
#pragma unroll
  for (int r = 0; r < 4; ++r) {
    int i = ic + r;
    bool v = i < HD;
    bsv[r] = v ? (bi[i] + bh[i]) : 0.0f;
    wx0[r] = (v && myL == 0) ? Wih1[i * 2 + 0] : 0.0f;
    wx1[r] = (v && myL == 0) ? Wih1[i * 2 + 1] : 0.0f;
  }

  const int selfBuf = myL;
  const int crossBuf = (myL > 0) ? myL - 1 : 0;
  const int ldsOff = l15 * KST + 8 * quad;

  const unsigned short* sbase = hbuf + selfBuf * LAY_SH + ldsOff;
  const unsigned short* cbase = hbuf + crossBuf * LAY_SH + ldsOff;
  unsigned short* wbase = hbuf + myL * LAY_SH + l15 * KST + ic;

  f16x8 pfC0 = f16x8(0), pfC1 = f16x8(0);  // cross B-frags for CURRENT iter

  __syncthreads();

  // one diagonal step: iter s computes h1_s, h2_{s-2}, h3_{s-4}
  auto step = [&](int s, int wr, int rd, bool act) {
    f16x8 bS0, bS1, pfN0, pfN1;
    if (act) {
      bS0 = *reinterpret_cast<const f16x8*>(sbase + rd * SLOT_SH);
      bS1 = *reinterpret_cast<const f16x8*>(sbase + rd * SLOT_SH + 32);
    }
    if (myL > 0) {  // prefetch cross frags for NEXT iter
      pfN0 = *reinterpret_cast<const f16x8*>(cbase + rd * SLOT_SH);
      pfN1 = *reinterpret_cast<const f16x8*>(cbase + rd * SLOT_SH + 32);
    }
    if (act) {
      f32x4 c;
      if (myL == 0) {
        float2 xc = *reinterpret_cast<const float2*>(&xls[s][2 * l15]);
        f32x4 ci;
#pragma unroll
        for (int r = 0; r < 4; ++r) ci[r] = fmaf(wx1[r], xc.y, fmaf(wx0[r], xc.x, bsv[r]));
        c = MFMA16(wA[0][0], bS0, ci, 0, 0, 0);
        c = MFMA16(wA[0][1], bS1, c, 0, 0, 0);
      } else {
        c = MFMA16(wA[0][0], pfC0, bsv, 0, 0, 0);
        c = MFMA16(wA[0][1], pfC1, c, 0, 0, 0);
        c = MFMA16(wA[1][0], bS0, c, 0, 0, 0);
        c = MFMA16(wA[1][1], bS1, c, 0, 0, 0);
      }
      // batched tanh: t = 1 - 2/(1+e^{2x}); ONE rcp for all 4 via product trick.
      // clamp |x|<=11: tanh(11) -> fp16 1.0 exactly; keeps product < f32-max.
      float d[4];
#pragma unroll
      for (int r = 0; r < 4; ++r) {
        float xr = __builtin_amdgcn_fmed3f(c[r], -11.0f, 11.0f);
        d[r] = __expf(2.0f * xr) + 1.0f;
      }
      float p01 = d[0] * d[1], p23 = d[2] * d[3];
      float rp = __builtin_amdgcn_rcpf(p01 * p23);
      float q01 = rp * p23, q23 = rp * p01;
      float iv[4] = {q01 * d[1], q01 * d[0], q23 * d[3], q23 * d[2]};
      unsigned short ht[4];
#pragma unroll
      for (int r = 0; r < 4; ++r) ht[r] = f2h(fmaf(-2.0f, iv[r], 1.0f));
      unsigned int h01 = (unsigned int)ht[0] | ((unsigned int)ht[1] << 16);
      unsigned int h23 = (unsigned int)ht[2] | ((unsigned int)ht[3] << 16);
      *reinterpret_cast<uint2*>(wbase + wr * SLOT_SH) = make_uint2(h01, h23);
    }
    if (myL > 0) { pfC0 = pfN0; pfC1 = pfN1; }
    __syncthreads();
  };

  auto actOf = [&](int s) {
    return (myL == 0) ? (s < T_STEPS)
         : (myL == 1) ? (s >= 2 && s < T_STEPS + 2)
                      : (s >= 4);
  };

  // prologue s=0..3
  for (int s = 0; s < 4; ++s) step(s, s % 3, (s + 2) % 3, actOf(s));
  // steady s=4..255: all waves active; literal ring slots
  for (int sb = 4; sb < 256; sb += 3) {
    step(sb + 0, 1, 0, true);
    step(sb + 1, 2, 1, true);
    step(sb + 2, 0, 2, true);
  }
  // epilogue s=256..259
  for (int s = 256; s < 260; ++s) step(s, s % 3, (s + 2) % 3, actOf(s));

  // ---- fc epilogue: h3_255 written at s=259 -> slot 259%3 = 1 ----
  if (tid < BT * 2) {
    int b = tid >> 1, o = tid & 1;
    const unsigned short* h3 = hbuf + 1 * SLOT_SH + 2 * LAY_SH + b * KST;
    float acc = fcb[o];
    for (int i = 0; i < HD; ++i) acc += fcw[o * HD + i] * h2f(h3[i]);
    out[(size_t)(b0 + b) * 2 + o] = acc;
  }
}

}  // namespace

extern "C" void kernel_launch(void* const* d_in, const int* in_sizes, int n_in,
                              void* d_out, int out_size, void* d_ws, size_t ws_size,
                              hipStream_t stream) {
  const float* x = (const float*)d_in[0];
  const float* Wih1 = (const float*)d_in[1];
  const float* Whh1 = (const float*)d_in[2];
  const float* bih1 = (const float*)d_in[3];
  const float* bhh1 = (const float*)d_in[4];
  const float* Wih2 = (const float*)d_in[5];
  const float* Whh2 = (const float*)d_in[6];
  const float* bih2 = (const float*)d_in[7];
  const float* bhh2 = (const float*)d_in[8];
  const float* Wih3 = (const float*)d_in[9];
  const float* Whh3 = (const float*)d_in[10];
  const float* bih3 = (const float*)d_in[11];
  const float* bhh3 = (const float*)d_in[12];
  const float* fcw = (const float*)d_in[13];
  const float* fcb = (const float*)d_in[14];

  rnn3_kernel<<<4096 / BT, NTHR, 0, stream>>>(x, Wih1, Whh1, bih1, bhh1,
                                              Wih2, Whh2, bih2, bhh2,
                                              Wih3, Whh3, bih3, bhh3,
                                              fcw, fcb, (float*)d_out);
}